// Round 4
// baseline (1566.108 us; speedup 1.0000x reference)
//
#include <hip/hip_runtime.h>
#include <stdint.h>

#define WAVE 64
#define CIN 64
#define COUT 64
#define KS 5
#define KTOT 125  // 5^3

__device__ inline unsigned long long wmin64(unsigned long long v) {
#pragma unroll
  for (int o = 32; o >= 1; o >>= 1) {
    unsigned long long u = __shfl_xor(v, o, 64);
    v = (u < v) ? u : v;
  }
  return v;
}

__device__ inline unsigned f32_orderable(float f) {
  unsigned fb = __float_as_uint(f);
  return (fb & 0x80000000u) ? ~fb : (fb | 0x80000000u);
}
__device__ inline float f32_unorderable(unsigned u) {
  unsigned fb = (u & 0x80000000u) ? (u & 0x7fffffffu) : ~u;
  return __uint_as_float(fb);
}

__device__ inline void edge_basis(const float* __restrict__ pseudo, int e,
                                  float bas[8], int kidx[8]) {
  float v0 = pseudo[e * 3 + 0] * (float)(KS - 1);
  float v1 = pseudo[e * 3 + 1] * (float)(KS - 1);
  float v2 = pseudo[e * 3 + 2] * (float)(KS - 1);
  float l0 = floorf(v0), l1 = floorf(v1), l2 = floorf(v2);
  float f0 = v0 - l0, f1 = v1 - l1, f2 = v2 - l2;
  int i0 = (int)l0, i1 = (int)l1, i2 = (int)l2;
#pragma unroll
  for (int s = 0; s < 8; s++) {
    int b0 = s & 1, b1 = (s >> 1) & 1, b2 = (s >> 2) & 1;
    float bb = (b0 ? f0 : 1.f - f0) * (b1 ? f1 : 1.f - f1) * (b2 ? f2 : 1.f - f2);
    int j0 = i0 + b0; j0 = j0 < 0 ? 0 : (j0 > KS - 1 ? KS - 1 : j0);
    int j1 = i1 + b1; j1 = j1 < 0 ? 0 : (j1 > KS - 1 ? KS - 1 : j1);
    int j2 = i2 + b2; j2 = j2 < 0 ? 0 : (j2 > KS - 1 ? KS - 1 : j2);
    bas[s] = bb;
    kidx[s] = j0 + KS * j1 + KS * KS * j2;
  }
}

// ---------- B1: per-kidx record count (LDS histogram) ----------
__global__ void count_kernel(const float* __restrict__ pseudo,
                             int* __restrict__ hist, int E_) {
  __shared__ int lh[KTOT];
  int tid = threadIdx.x;
  for (int i = tid; i < KTOT; i += 256) lh[i] = 0;
  __syncthreads();
  int e = blockIdx.x * 256 + tid;
  if (e < E_) {
    float bas[8];
    int kidx[8];
    edge_basis(pseudo, e, bas, kidx);
#pragma unroll
    for (int s = 0; s < 8; s++) atomicAdd(&lh[kidx[s]], 1);
  }
  __syncthreads();
  for (int i = tid; i < KTOT; i += 256)
    if (lh[i]) atomicAdd(&hist[i], lh[i]);
}

// ---------- B2: serial scan -> 64-aligned bucket offsets, block->kidx map ----------
__global__ void scan_kernel(const int* __restrict__ hist, int* __restrict__ off,
                            int* __restrict__ cur, int* __restrict__ block2k,
                            int* __restrict__ meta) {
  if (threadIdx.x == 0 && blockIdx.x == 0) {
    int o = 0;
    for (int k = 0; k < KTOT; k++) {
      off[k] = o;
      cur[k] = o;
      int padded = (hist[k] + 63) & ~63;
      int nb = padded >> 6;
      int b0 = o >> 6;
      for (int b = 0; b < nb; b++) block2k[b0 + b] = k;
      o += padded;
    }
    off[KTOT] = o;
    meta[0] = o >> 6;  // number of 64-record blocks
  }
}

// ---------- B3: fill records (dst, src, basis) into kidx buckets ----------
__global__ void fill_kernel(const int* __restrict__ ei,
                            const float* __restrict__ pseudo,
                            int* __restrict__ cur,
                            int* __restrict__ rdst, int* __restrict__ rsrc,
                            float* __restrict__ rbas,
                            float* __restrict__ deg, int E_) {
  int e = blockIdx.x * 256 + threadIdx.x;
  if (e >= E_) return;
  int src = ei[e];
  int dst = ei[E_ + e];
  float bas[8];
  int kidx[8];
  edge_basis(pseudo, e, bas, kidx);
#pragma unroll
  for (int s = 0; s < 8; s++) {
    int pos = atomicAdd(&cur[kidx[s]], 1);
    rdst[pos] = dst;
    rsrc[pos] = src;
    rbas[pos] = bas[s];
  }
  atomicAdd(&deg[dst], 1.f);
}

// ---------- B4: grouped GEMM: per 64-record block, res = (bas*x[src]) @ W[kidx] ----------
__global__ __launch_bounds__(256) void grouped_gemm_kernel(
    const float* __restrict__ x, const float* __restrict__ Wf,
    const int* __restrict__ rdst, const int* __restrict__ rsrc,
    const float* __restrict__ rbas, const int* __restrict__ block2k,
    const int* __restrict__ meta, float* __restrict__ acc) {
  __shared__ float Wt[64][64];   // [i][o]
  __shared__ float Atr[64][64];  // [i][rec]
  int nb = meta[0];
  int bid = blockIdx.x;
  if (bid >= nb) return;
  int k = block2k[bid];
  int base = bid * 64;
  int tid = threadIdx.x;

  // stage W[k] (row-major [i][o]) — coalesced
  {
    int wi = tid >> 2, wo = (tid & 3) * 16;
    const float* wsrc = Wf + (size_t)k * (CIN * COUT) + wi * COUT + wo;
    float4 a = *(const float4*)wsrc;
    float4 b = *(const float4*)(wsrc + 4);
    float4 c = *(const float4*)(wsrc + 8);
    float4 d = *(const float4*)(wsrc + 12);
    *(float4*)&Wt[wi][wo + 0] = a;
    *(float4*)&Wt[wi][wo + 4] = b;
    *(float4*)&Wt[wi][wo + 8] = c;
    *(float4*)&Wt[wi][wo + 12] = d;
  }
  // stage A^T: Atr[i][rec] = bas * x[src][i]  (pad recs have bas=0, src=0)
  {
    int rec = tid >> 2, c16 = (tid & 3) * 16;
    int slot = base + rec;
    float b = rbas[slot];
    int s = rsrc[slot];
    const float* xs = x + (size_t)s * CIN + c16;
    float4 v0 = *(const float4*)xs;
    float4 v1 = *(const float4*)(xs + 4);
    float4 v2 = *(const float4*)(xs + 8);
    float4 v3 = *(const float4*)(xs + 12);
    Atr[c16 + 0][rec] = b * v0.x;  Atr[c16 + 1][rec] = b * v0.y;
    Atr[c16 + 2][rec] = b * v0.z;  Atr[c16 + 3][rec] = b * v0.w;
    Atr[c16 + 4][rec] = b * v1.x;  Atr[c16 + 5][rec] = b * v1.y;
    Atr[c16 + 6][rec] = b * v1.z;  Atr[c16 + 7][rec] = b * v1.w;
    Atr[c16 + 8][rec] = b * v2.x;  Atr[c16 + 9][rec] = b * v2.y;
    Atr[c16 + 10][rec] = b * v2.z; Atr[c16 + 11][rec] = b * v2.w;
    Atr[c16 + 12][rec] = b * v3.x; Atr[c16 + 13][rec] = b * v3.y;
    Atr[c16 + 14][rec] = b * v3.z; Atr[c16 + 15][rec] = b * v3.w;
  }
  __syncthreads();

  int mg = tid >> 4, og = tid & 15;
  int m = mg * 4, o = og * 4;
  float a_[4][4] = {};
#pragma unroll 16
  for (int kk = 0; kk < 64; kk++) {
    float4 av = *(const float4*)&Atr[kk][m];
    float4 wv = *(const float4*)&Wt[kk][o];
    a_[0][0] = fmaf(av.x, wv.x, a_[0][0]);
    a_[0][1] = fmaf(av.x, wv.y, a_[0][1]);
    a_[0][2] = fmaf(av.x, wv.z, a_[0][2]);
    a_[0][3] = fmaf(av.x, wv.w, a_[0][3]);
    a_[1][0] = fmaf(av.y, wv.x, a_[1][0]);
    a_[1][1] = fmaf(av.y, wv.y, a_[1][1]);
    a_[1][2] = fmaf(av.y, wv.z, a_[1][2]);
    a_[1][3] = fmaf(av.y, wv.w, a_[1][3]);
    a_[2][0] = fmaf(av.z, wv.x, a_[2][0]);
    a_[2][1] = fmaf(av.z, wv.y, a_[2][1]);
    a_[2][2] = fmaf(av.z, wv.z, a_[2][2]);
    a_[2][3] = fmaf(av.z, wv.w, a_[2][3]);
    a_[3][0] = fmaf(av.w, wv.x, a_[3][0]);
    a_[3][1] = fmaf(av.w, wv.y, a_[3][1]);
    a_[3][2] = fmaf(av.w, wv.z, a_[3][2]);
    a_[3][3] = fmaf(av.w, wv.w, a_[3][3]);
  }

#pragma unroll
  for (int i = 0; i < 4; i++) {
    int dst = rdst[base + m + i];
#pragma unroll
    for (int j = 0; j < 4; j++) {
      atomicAdd(&acc[(size_t)dst * COUT + o + j], a_[i][j]);
    }
  }
}

// ---------- node finish: acc/deg + x@root + bias, ELU ----------
__global__ void node_finish_kernel(const float* __restrict__ x,
                                   const float* __restrict__ root,
                                   const float* __restrict__ bias,
                                   const float* __restrict__ acc,
                                   const float* __restrict__ deg,
                                   float* __restrict__ h, int Nx_) {
  int lane = threadIdx.x & 63;
  int n = (int)((blockIdx.x * blockDim.x + threadIdx.x) >> 6);
  if (n >= Nx_) return;
  float xs = x[(size_t)n * CIN + lane];
  float r = 0.f;
#pragma unroll 4
  for (int i = 0; i < CIN; i++) {
    float xv = __shfl(xs, i, 64);
    r = fmaf(xv, root[i * COUT + lane], r);
  }
  float d = deg[n];
  d = d > 1.f ? d : 1.f;
  float o = acc[(size_t)n * COUT + lane] / d + r + bias[lane];
  h[(size_t)n * COUT + lane] = (o > 0.f) ? o : expm1f(o);
}

// ---------- kNN pre-pack: [x0,x1,x2,|x|^2] ----------
__global__ void pack_posx_kernel(const float* __restrict__ pos_x,
                                 float4* __restrict__ pxp, int Nx_) {
  int t = blockIdx.x * blockDim.x + threadIdx.x;
  if (t >= Nx_) return;
  float a0 = pos_x[t * 3 + 0], a1 = pos_x[t * 3 + 1], a2 = pos_x[t * 3 + 2];
  pxp[t] = make_float4(a0, a1, a2, a0 * a0 + a1 * a1 + a2 * a2);
}

// ---------- fused kNN + inverse-distance interp (k-specialized) ----------
__global__ void knn_interp2_kernel(const float* __restrict__ h,
                                   const float4* __restrict__ pxp,
                                   const float* __restrict__ pos_y,
                                   const int* __restrict__ batch_x,
                                   const int* __restrict__ batch_y,
                                   const int* __restrict__ kptr,
                                   float* __restrict__ out,
                                   int Nx_, int Ny_) {
  int lane = threadIdx.x & 63;
  int yy = (int)((blockIdx.x * blockDim.x + threadIdx.x) >> 6);
  if (yy >= Ny_) return;

  float q0 = pos_y[yy * 3 + 0], q1 = pos_y[yy * 3 + 1], q2 = pos_y[yy * 3 + 2];
  float py2 = q0 * q0 + q1 * q1 + q2 * q2;
  int by = batch_y[yy];
  int kk = *kptr;
  kk = kk < 1 ? 1 : (kk > 8 ? 8 : kk);

  float num = 0.f, den = 0.f;

  if (kk <= 3) {
    const float FINF = __uint_as_float(0x7f800000u);
    float bd0 = FINF, bd1 = FINF, bd2 = FINF;
    unsigned bi0 = ~0u, bi1 = ~0u, bi2 = ~0u;

    for (int t0 = 0; t0 < Nx_; t0 += 64) {
      int t = t0 + lane;
      int tc = t < Nx_ ? t : Nx_ - 1;
      float4 p = pxp[tc];
      float dot = fmaf(q0, p.x, fmaf(q1, p.y, q2 * p.z));
      float d2 = fmaf(-2.f, dot, py2 + p.w);
      if (batch_x[tc] != by) d2 = 1e10f;
      if (t >= Nx_) d2 = FINF;

      float kv = d2;
      unsigned ki = (unsigned)t;
      {
        bool lt = kv < bd0;
        float nv = lt ? kv : bd0; float xv = lt ? bd0 : kv;
        unsigned ni = lt ? ki : bi0; unsigned xi = lt ? bi0 : ki;
        bd0 = nv; bi0 = ni; kv = xv; ki = xi;
      }
      {
        bool lt = kv < bd1;
        float nv = lt ? kv : bd1; float xv = lt ? bd1 : kv;
        unsigned ni = lt ? ki : bi1; unsigned xi = lt ? bi1 : ki;
        bd1 = nv; bi1 = ni; kv = xv; ki = xi;
      }
      {
        bool lt = kv < bd2;
        float nv = lt ? kv : bd2;
        unsigned ni = lt ? ki : bi2;
        bd2 = nv; bi2 = ni;
      }
    }

    unsigned long long c0 = (((unsigned long long)f32_orderable(bd0)) << 32) | bi0;
    unsigned long long c1 = (((unsigned long long)f32_orderable(bd1)) << 32) | bi1;
    unsigned long long c2 = (((unsigned long long)f32_orderable(bd2)) << 32) | bi2;

    for (int j = 0; j < kk; j++) {
      unsigned long long m = wmin64(c0);
      if (c0 == m) { c0 = c1; c1 = c2; c2 = ~0ull; }
      unsigned u = (unsigned)(m >> 32);
      int idx = (int)(m & 0xffffffffu);
      idx = (idx < 0 || idx >= Nx_) ? 0 : idx;
      float d2 = f32_unorderable(u);
      float w = 1.f / fmaxf(d2, 1e-16f);
      num = fmaf(w, h[(size_t)idx * COUT + lane], num);
      den += w;
    }
  } else {
    unsigned long long best[8];
#pragma unroll
    for (int j = 0; j < 8; j++) best[j] = ~0ull;

    for (int t0 = 0; t0 < Nx_; t0 += 64) {
      int t = t0 + lane;
      unsigned long long key = ~0ull;
      if (t < Nx_) {
        float4 p = pxp[t];
        float dot = fmaf(q0, p.x, fmaf(q1, p.y, q2 * p.z));
        float d2 = fmaf(-2.f, dot, py2 + p.w);
        if (batch_x[t] != by) d2 = 1e10f;
        key = (((unsigned long long)f32_orderable(d2)) << 32) | (unsigned)t;
      }
      if (key < best[7]) {
#pragma unroll
        for (int j = 0; j < 8; j++) {
          unsigned long long mn = key < best[j] ? key : best[j];
          unsigned long long mx = key < best[j] ? best[j] : key;
          best[j] = mn;
          key = mx;
        }
      }
    }

    for (int j = 0; j < kk; j++) {
      unsigned long long m = wmin64(best[0]);
      if (best[0] == m) {
#pragma unroll
        for (int t = 0; t < 7; t++) best[t] = best[t + 1];
        best[7] = ~0ull;
      }
      unsigned u = (unsigned)(m >> 32);
      int idx = (int)(m & 0xffffffffu);
      idx = (idx < 0 || idx >= Nx_) ? 0 : idx;
      float d2 = f32_unorderable(u);
      float w = 1.f / fmaxf(d2, 1e-16f);
      num = fmaf(w, h[(size_t)idx * COUT + lane], num);
      den += w;
    }
  }

  out[(size_t)yy * COUT + lane] = num / den;
}

extern "C" void kernel_launch(void* const* d_in, const int* in_sizes, int n_in,
                              void* d_out, int out_size, void* d_ws, size_t ws_size,
                              hipStream_t stream) {
  const float* x = (const float*)d_in[0];
  const float* pos_x = (const float*)d_in[1];
  const float* pos_y = (const float*)d_in[2];
  const int* eidx = (const int*)d_in[3];
  const float* pseudo = (const float*)d_in[4];
  const int* batch_x = (const int*)d_in[5];
  const int* batch_y = (const int*)d_in[6];
  const float* W = (const float*)d_in[7];   // [125,64,64]
  const float* root = (const float*)d_in[8];
  const float* bias = (const float*)d_in[9];
  const int* kptr = (const int*)d_in[10];

  int Nx = in_sizes[0] / CIN;
  int Ny = in_sizes[2] / 3;
  int E = in_sizes[3] / 2;

  int maxslots = E * 8 + KTOT * 64;  // padded record capacity
  int maxblocks = maxslots / 64 + 1;

  // ws layout (4B units):
  // acc[Nx*64] | deg[Nx] | h[Nx*64] | pxp[Nx*4] | hist[128] | off[128] |
  // cur[128] | meta[16] | block2k[maxblocks(pad16)] | rdst[ms] | rsrc[ms] | rbas[ms]
  float* acc = (float*)d_ws;
  float* deg = acc + (size_t)Nx * COUT;
  float* h = deg + Nx;
  float4* pxp = (float4*)(h + (size_t)Nx * COUT);
  int* hist = (int*)(pxp + Nx);
  int* off = hist + 128;
  int* cur = off + 128;
  int* meta = cur + 128;
  int* block2k = meta + 16;
  int b2k_pad = (maxblocks + 15) & ~15;
  int* rdst = block2k + b2k_pad;
  int* rsrc = rdst + maxslots;
  float* rbas = (float*)(rsrc + maxslots);

  float* out = (float*)d_out;

  // zero: acc+deg, hist, rec arrays (rdst|rsrc|rbas contiguous)
  hipMemsetAsync(acc, 0, ((size_t)Nx * COUT + Nx) * sizeof(float), stream);
  hipMemsetAsync(hist, 0, 128 * sizeof(int), stream);
  hipMemsetAsync(rdst, 0, (size_t)3 * maxslots * sizeof(int), stream);

  int eblocks = (E + 255) / 256;
  count_kernel<<<eblocks, 256, 0, stream>>>(pseudo, hist, E);
  scan_kernel<<<1, 64, 0, stream>>>(hist, off, cur, block2k, meta);
  fill_kernel<<<eblocks, 256, 0, stream>>>(eidx, pseudo, cur, rdst, rsrc, rbas, deg, E);
  grouped_gemm_kernel<<<maxslots / 64, 256, 0, stream>>>(x, W, rdst, rsrc, rbas,
                                                         block2k, meta, acc);
  {
    int blocks = (Nx * WAVE + 255) / 256;
    node_finish_kernel<<<blocks, 256, 0, stream>>>(x, root, bias, acc, deg, h, Nx);
  }
  pack_posx_kernel<<<(Nx + 255) / 256, 256, 0, stream>>>(pos_x, pxp, Nx);
  {
    int blocks = (Ny * WAVE + 255) / 256;
    knn_interp2_kernel<<<blocks, 256, 0, stream>>>(h, pxp, pos_y, batch_x, batch_y,
                                                   kptr, out, Nx, Ny);
  }
}

// Round 5
// 829.786 us; speedup vs baseline: 1.8874x; 1.8874x over previous
//
#include <hip/hip_runtime.h>
#include <stdint.h>

#define WAVE 64
#define CIN 64
#define COUT 64
#define KS 5
#define KTOT 125  // 5^3

__device__ inline unsigned long long wmin64(unsigned long long v) {
#pragma unroll
  for (int o = 32; o >= 1; o >>= 1) {
    unsigned long long u = __shfl_xor(v, o, 64);
    v = (u < v) ? u : v;
  }
  return v;
}

__device__ inline unsigned f32_orderable(float f) {
  unsigned fb = __float_as_uint(f);
  return (fb & 0x80000000u) ? ~fb : (fb | 0x80000000u);
}
__device__ inline float f32_unorderable(unsigned u) {
  unsigned fb = (u & 0x80000000u) ? (u & 0x7fffffffu) : ~u;
  return __uint_as_float(fb);
}

__device__ inline void edge_basis(const float* __restrict__ pseudo, int e,
                                  float bas[8], int kidx[8]) {
  float v0 = pseudo[e * 3 + 0] * (float)(KS - 1);
  float v1 = pseudo[e * 3 + 1] * (float)(KS - 1);
  float v2 = pseudo[e * 3 + 2] * (float)(KS - 1);
  float l0 = floorf(v0), l1 = floorf(v1), l2 = floorf(v2);
  float f0 = v0 - l0, f1 = v1 - l1, f2 = v2 - l2;
  int i0 = (int)l0, i1 = (int)l1, i2 = (int)l2;
#pragma unroll
  for (int s = 0; s < 8; s++) {
    int b0 = s & 1, b1 = (s >> 1) & 1, b2 = (s >> 2) & 1;
    float bb = (b0 ? f0 : 1.f - f0) * (b1 ? f1 : 1.f - f1) * (b2 ? f2 : 1.f - f2);
    int j0 = i0 + b0; j0 = j0 < 0 ? 0 : (j0 > KS - 1 ? KS - 1 : j0);
    int j1 = i1 + b1; j1 = j1 < 0 ? 0 : (j1 > KS - 1 ? KS - 1 : j1);
    int j2 = i2 + b2; j2 = j2 < 0 ? 0 : (j2 > KS - 1 ? KS - 1 : j2);
    bas[s] = bb;
    kidx[s] = j0 + KS * j1 + KS * KS * j2;
  }
}

// ---------- B1: per-kidx record count (LDS histogram) ----------
__global__ void count_kernel(const float* __restrict__ pseudo,
                             int* __restrict__ hist, int E_) {
  __shared__ int lh[KTOT];
  int tid = threadIdx.x;
  for (int i = tid; i < KTOT; i += 256) lh[i] = 0;
  __syncthreads();
  int e = blockIdx.x * 256 + tid;
  if (e < E_) {
    float bas[8];
    int kidx[8];
    edge_basis(pseudo, e, bas, kidx);
#pragma unroll
    for (int s = 0; s < 8; s++) atomicAdd(&lh[kidx[s]], 1);
  }
  __syncthreads();
  for (int i = tid; i < KTOT; i += 256)
    if (lh[i]) atomicAdd(&hist[i], lh[i]);
}

// ---------- B2: serial scan -> 64-aligned bucket offsets (125 iters only) ----------
__global__ void scan_kernel(const int* __restrict__ hist, int* __restrict__ off,
                            int* __restrict__ cur, int* __restrict__ meta) {
  if (threadIdx.x == 0 && blockIdx.x == 0) {
    int o = 0;
    for (int k = 0; k < KTOT; k++) {
      off[k] = o;
      cur[k] = o;
      o += (hist[k] + 63) & ~63;
    }
    off[KTOT] = o;
    meta[0] = o >> 6;  // number of 64-record blocks
  }
}

// ---------- B3: fill records (dst, src, basis) into kidx buckets ----------
__global__ void fill_kernel(const int* __restrict__ ei,
                            const float* __restrict__ pseudo,
                            int* __restrict__ cur,
                            int* __restrict__ rdst, int* __restrict__ rsrc,
                            float* __restrict__ rbas,
                            float* __restrict__ deg, int E_) {
  int e = blockIdx.x * 256 + threadIdx.x;
  if (e >= E_) return;
  int src = ei[e];
  int dst = ei[E_ + e];
  float bas[8];
  int kidx[8];
  edge_basis(pseudo, e, bas, kidx);
#pragma unroll
  for (int s = 0; s < 8; s++) {
    int pos = atomicAdd(&cur[kidx[s]], 1);
    rdst[pos] = dst;
    rsrc[pos] = src;
    rbas[pos] = bas[s];
  }
  atomicAdd(&deg[dst], 1.f);
}

// ---------- B4: grouped GEMM, coalesced-burst atomic epilogue ----------
__global__ __launch_bounds__(256) void grouped_gemm_kernel(
    const float* __restrict__ x, const float* __restrict__ Wf,
    const int* __restrict__ rdst, const int* __restrict__ rsrc,
    const float* __restrict__ rbas, const int* __restrict__ off,
    const int* __restrict__ meta, float* __restrict__ acc) {
  __shared__ float Wt[64][64];   // [i][o]
  __shared__ float Atr[64][64];  // [i][rec], reused as res[rec][o] in epilogue
  __shared__ int kshare;
  int nb = meta[0];
  int bid = blockIdx.x;
  if (bid >= nb) return;
  int tid = threadIdx.x;
  int base = bid << 6;

  if (tid == 0) {
    // largest k with off[k] <= base  (off is 64-aligned, off[KTOT] = total)
    int lo = 0, hi = KTOT;
    while (lo + 1 < hi) {
      int mid = (lo + hi) >> 1;
      if (off[mid] <= base) lo = mid; else hi = mid;
    }
    kshare = lo;
  }

  // stage A^T: Atr[i][rec] = bas * x[src][i]  (pad recs have bas=0)
  {
    int rec = tid >> 2, c16 = (tid & 3) * 16;
    int slot = base + rec;
    float b = rbas[slot];
    int s = rsrc[slot];
    const float* xs = x + (size_t)s * CIN + c16;
    float4 v0 = *(const float4*)xs;
    float4 v1 = *(const float4*)(xs + 4);
    float4 v2 = *(const float4*)(xs + 8);
    float4 v3 = *(const float4*)(xs + 12);
    Atr[c16 + 0][rec] = b * v0.x;  Atr[c16 + 1][rec] = b * v0.y;
    Atr[c16 + 2][rec] = b * v0.z;  Atr[c16 + 3][rec] = b * v0.w;
    Atr[c16 + 4][rec] = b * v1.x;  Atr[c16 + 5][rec] = b * v1.y;
    Atr[c16 + 6][rec] = b * v1.z;  Atr[c16 + 7][rec] = b * v1.w;
    Atr[c16 + 8][rec] = b * v2.x;  Atr[c16 + 9][rec] = b * v2.y;
    Atr[c16 + 10][rec] = b * v2.z; Atr[c16 + 11][rec] = b * v2.w;
    Atr[c16 + 12][rec] = b * v3.x; Atr[c16 + 13][rec] = b * v3.y;
    Atr[c16 + 14][rec] = b * v3.z; Atr[c16 + 15][rec] = b * v3.w;
  }
  __syncthreads();  // kshare visible

  // stage W[k] (row-major [i][o]) — coalesced float4
  {
    int k = kshare;
    int wi = tid >> 2, wo = (tid & 3) * 16;
    const float* wsrc = Wf + (size_t)k * (CIN * COUT) + wi * COUT + wo;
    float4 a = *(const float4*)wsrc;
    float4 b = *(const float4*)(wsrc + 4);
    float4 c = *(const float4*)(wsrc + 8);
    float4 d = *(const float4*)(wsrc + 12);
    *(float4*)&Wt[wi][wo + 0] = a;
    *(float4*)&Wt[wi][wo + 4] = b;
    *(float4*)&Wt[wi][wo + 8] = c;
    *(float4*)&Wt[wi][wo + 12] = d;
  }
  __syncthreads();

  int mg = tid >> 4, og = tid & 15;
  int m = mg * 4, o = og * 4;
  float a_[4][4] = {};
#pragma unroll 16
  for (int kk = 0; kk < 64; kk++) {
    float4 av = *(const float4*)&Atr[kk][m];
    float4 wv = *(const float4*)&Wt[kk][o];
    a_[0][0] = fmaf(av.x, wv.x, a_[0][0]);
    a_[0][1] = fmaf(av.x, wv.y, a_[0][1]);
    a_[0][2] = fmaf(av.x, wv.z, a_[0][2]);
    a_[0][3] = fmaf(av.x, wv.w, a_[0][3]);
    a_[1][0] = fmaf(av.y, wv.x, a_[1][0]);
    a_[1][1] = fmaf(av.y, wv.y, a_[1][1]);
    a_[1][2] = fmaf(av.y, wv.z, a_[1][2]);
    a_[1][3] = fmaf(av.y, wv.w, a_[1][3]);
    a_[2][0] = fmaf(av.z, wv.x, a_[2][0]);
    a_[2][1] = fmaf(av.z, wv.y, a_[2][1]);
    a_[2][2] = fmaf(av.z, wv.z, a_[2][2]);
    a_[2][3] = fmaf(av.z, wv.w, a_[2][3]);
    a_[3][0] = fmaf(av.w, wv.x, a_[3][0]);
    a_[3][1] = fmaf(av.w, wv.y, a_[3][1]);
    a_[3][2] = fmaf(av.w, wv.z, a_[3][2]);
    a_[3][3] = fmaf(av.w, wv.w, a_[3][3]);
  }

  // epilogue: results -> LDS (reuse Atr as res[rec][o]) -> per-row coalesced bursts
  __syncthreads();  // all Atr/Wt reads done
  float* res = &Atr[0][0];
#pragma unroll
  for (int i = 0; i < 4; i++) {
    *(float4*)&res[(m + i) * 64 + o] =
        make_float4(a_[i][0], a_[i][1], a_[i][2], a_[i][3]);
  }
  __syncthreads();

  int wave = tid >> 6, lane = tid & 63;
#pragma unroll 4
  for (int p = 0; p < 16; p++) {
    int r = wave * 16 + p;
    float v = res[r * 64 + lane];
    if (__ballot(v != 0.f) == 0ull) continue;  // skip all-zero pad rows
    int dst = rdst[base + r];
    atomicAdd(&acc[(size_t)dst * COUT + lane], v);  // one 256B burst per row
  }
}

// ---------- node finish: acc/deg + x@root + bias, ELU ----------
__global__ void node_finish_kernel(const float* __restrict__ x,
                                   const float* __restrict__ root,
                                   const float* __restrict__ bias,
                                   const float* __restrict__ acc,
                                   const float* __restrict__ deg,
                                   float* __restrict__ h, int Nx_) {
  int lane = threadIdx.x & 63;
  int n = (int)((blockIdx.x * blockDim.x + threadIdx.x) >> 6);
  if (n >= Nx_) return;
  float xs = x[(size_t)n * CIN + lane];
  float r = 0.f;
#pragma unroll 4
  for (int i = 0; i < CIN; i++) {
    float xv = __shfl(xs, i, 64);
    r = fmaf(xv, root[i * COUT + lane], r);
  }
  float d = deg[n];
  d = d > 1.f ? d : 1.f;
  float o = acc[(size_t)n * COUT + lane] / d + r + bias[lane];
  h[(size_t)n * COUT + lane] = (o > 0.f) ? o : expm1f(o);
}

// ---------- kNN pre-pack: [x0,x1,x2,|x|^2] ----------
__global__ void pack_posx_kernel(const float* __restrict__ pos_x,
                                 float4* __restrict__ pxp, int Nx_) {
  int t = blockIdx.x * blockDim.x + threadIdx.x;
  if (t >= Nx_) return;
  float a0 = pos_x[t * 3 + 0], a1 = pos_x[t * 3 + 1], a2 = pos_x[t * 3 + 2];
  pxp[t] = make_float4(a0, a1, a2, a0 * a0 + a1 * a1 + a2 * a2);
}

// ---------- fused kNN + inverse-distance interp (k-specialized) ----------
__global__ void knn_interp2_kernel(const float* __restrict__ h,
                                   const float4* __restrict__ pxp,
                                   const float* __restrict__ pos_y,
                                   const int* __restrict__ batch_x,
                                   const int* __restrict__ batch_y,
                                   const int* __restrict__ kptr,
                                   float* __restrict__ out,
                                   int Nx_, int Ny_) {
  int lane = threadIdx.x & 63;
  int yy = (int)((blockIdx.x * blockDim.x + threadIdx.x) >> 6);
  if (yy >= Ny_) return;

  float q0 = pos_y[yy * 3 + 0], q1 = pos_y[yy * 3 + 1], q2 = pos_y[yy * 3 + 2];
  float py2 = q0 * q0 + q1 * q1 + q2 * q2;
  int by = batch_y[yy];
  int kk = *kptr;
  kk = kk < 1 ? 1 : (kk > 8 ? 8 : kk);

  float num = 0.f, den = 0.f;

  if (kk <= 3) {
    const float FINF = __uint_as_float(0x7f800000u);
    float bd0 = FINF, bd1 = FINF, bd2 = FINF;
    unsigned bi0 = ~0u, bi1 = ~0u, bi2 = ~0u;

    for (int t0 = 0; t0 < Nx_; t0 += 64) {
      int t = t0 + lane;
      int tc = t < Nx_ ? t : Nx_ - 1;
      float4 p = pxp[tc];
      float dot = fmaf(q0, p.x, fmaf(q1, p.y, q2 * p.z));
      float d2 = fmaf(-2.f, dot, py2 + p.w);
      if (batch_x[tc] != by) d2 = 1e10f;
      if (t >= Nx_) d2 = FINF;

      float kv = d2;
      unsigned ki = (unsigned)t;
      {
        bool lt = kv < bd0;
        float nv = lt ? kv : bd0; float xv = lt ? bd0 : kv;
        unsigned ni = lt ? ki : bi0; unsigned xi = lt ? bi0 : ki;
        bd0 = nv; bi0 = ni; kv = xv; ki = xi;
      }
      {
        bool lt = kv < bd1;
        float nv = lt ? kv : bd1; float xv = lt ? bd1 : kv;
        unsigned ni = lt ? ki : bi1; unsigned xi = lt ? bi1 : ki;
        bd1 = nv; bi1 = ni; kv = xv; ki = xi;
      }
      {
        bool lt = kv < bd2;
        float nv = lt ? kv : bd2;
        unsigned ni = lt ? ki : bi2;
        bd2 = nv; bi2 = ni;
      }
    }

    unsigned long long c0 = (((unsigned long long)f32_orderable(bd0)) << 32) | bi0;
    unsigned long long c1 = (((unsigned long long)f32_orderable(bd1)) << 32) | bi1;
    unsigned long long c2 = (((unsigned long long)f32_orderable(bd2)) << 32) | bi2;

    for (int j = 0; j < kk; j++) {
      unsigned long long m = wmin64(c0);
      if (c0 == m) { c0 = c1; c1 = c2; c2 = ~0ull; }
      unsigned u = (unsigned)(m >> 32);
      int idx = (int)(m & 0xffffffffu);
      idx = (idx < 0 || idx >= Nx_) ? 0 : idx;
      float d2 = f32_unorderable(u);
      float w = 1.f / fmaxf(d2, 1e-16f);
      num = fmaf(w, h[(size_t)idx * COUT + lane], num);
      den += w;
    }
  } else {
    unsigned long long best[8];
#pragma unroll
    for (int j = 0; j < 8; j++) best[j] = ~0ull;

    for (int t0 = 0; t0 < Nx_; t0 += 64) {
      int t = t0 + lane;
      unsigned long long key = ~0ull;
      if (t < Nx_) {
        float4 p = pxp[t];
        float dot = fmaf(q0, p.x, fmaf(q1, p.y, q2 * p.z));
        float d2 = fmaf(-2.f, dot, py2 + p.w);
        if (batch_x[t] != by) d2 = 1e10f;
        key = (((unsigned long long)f32_orderable(d2)) << 32) | (unsigned)t;
      }
      if (key < best[7]) {
#pragma unroll
        for (int j = 0; j < 8; j++) {
          unsigned long long mn = key < best[j] ? key : best[j];
          unsigned long long mx = key < best[j] ? best[j] : key;
          best[j] = mn;
          key = mx;
        }
      }
    }

    for (int j = 0; j < kk; j++) {
      unsigned long long m = wmin64(best[0]);
      if (best[0] == m) {
#pragma unroll
        for (int t = 0; t < 7; t++) best[t] = best[t + 1];
        best[7] = ~0ull;
      }
      unsigned u = (unsigned)(m >> 32);
      int idx = (int)(m & 0xffffffffu);
      idx = (idx < 0 || idx >= Nx_) ? 0 : idx;
      float d2 = f32_unorderable(u);
      float w = 1.f / fmaxf(d2, 1e-16f);
      num = fmaf(w, h[(size_t)idx * COUT + lane], num);
      den += w;
    }
  }

  out[(size_t)yy * COUT + lane] = num / den;
}

extern "C" void kernel_launch(void* const* d_in, const int* in_sizes, int n_in,
                              void* d_out, int out_size, void* d_ws, size_t ws_size,
                              hipStream_t stream) {
  const float* x = (const float*)d_in[0];
  const float* pos_x = (const float*)d_in[1];
  const float* pos_y = (const float*)d_in[2];
  const int* eidx = (const int*)d_in[3];
  const float* pseudo = (const float*)d_in[4];
  const int* batch_x = (const int*)d_in[5];
  const int* batch_y = (const int*)d_in[6];
  const float* W = (const float*)d_in[7];   // [125,64,64]
  const float* root = (const float*)d_in[8];
  const float* bias = (const float*)d_in[9];
  const int* kptr = (const int*)d_in[10];

  int Nx = in_sizes[0] / CIN;
  int Ny = in_sizes[2] / 3;
  int E = in_sizes[3] / 2;

  int maxslots = E * 8 + KTOT * 64;  // padded record capacity
  int maxblocks = maxslots / 64;

  // ws layout (4B units):
  // acc[Nx*64] | deg[Nx] | h[Nx*64] | pxp[Nx*4] | hist[128] | off[128] |
  // cur[128] | meta[16] | rdst[ms] | rsrc[ms] | rbas[ms]
  float* acc = (float*)d_ws;
  float* deg = acc + (size_t)Nx * COUT;
  float* h = deg + Nx;
  float4* pxp = (float4*)(h + (size_t)Nx * COUT);
  int* hist = (int*)(pxp + Nx);
  int* off = hist + 128;
  int* cur = off + 128;
  int* meta = cur + 128;
  int* rdst = meta + 16;
  int* rsrc = rdst + maxslots;
  float* rbas = (float*)(rsrc + maxslots);

  float* out = (float*)d_out;

  // zero: acc+deg, hist, rec arrays (rdst|rsrc|rbas contiguous)
  hipMemsetAsync(acc, 0, ((size_t)Nx * COUT + Nx) * sizeof(float), stream);
  hipMemsetAsync(hist, 0, 128 * sizeof(int), stream);
  hipMemsetAsync(rdst, 0, (size_t)3 * maxslots * sizeof(int), stream);

  int eblocks = (E + 255) / 256;
  count_kernel<<<eblocks, 256, 0, stream>>>(pseudo, hist, E);
  scan_kernel<<<1, 64, 0, stream>>>(hist, off, cur, meta);
  fill_kernel<<<eblocks, 256, 0, stream>>>(eidx, pseudo, cur, rdst, rsrc, rbas, deg, E);
  grouped_gemm_kernel<<<maxblocks, 256, 0, stream>>>(x, W, rdst, rsrc, rbas,
                                                     off, meta, acc);
  {
    int blocks = (Nx * WAVE + 255) / 256;
    node_finish_kernel<<<blocks, 256, 0, stream>>>(x, root, bias, acc, deg, h, Nx);
  }
  pack_posx_kernel<<<(Nx + 255) / 256, 256, 0, stream>>>(pos_x, pxp, Nx);
  {
    int blocks = (Ny * WAVE + 255) / 256;
    knn_interp2_kernel<<<blocks, 256, 0, stream>>>(h, pxp, pos_y, batch_x, batch_y,
                                                   kptr, out, Nx, Ny);
  }
}

// Round 6
// 251.904 us; speedup vs baseline: 6.2171x; 3.2941x over previous
//
#include <hip/hip_runtime.h>
#include <stdint.h>

#define WAVE 64
#define CIN 64
#define COUT 64
#define KS 5
#define KTOT 125  // 5^3

__device__ inline unsigned long long wmin64(unsigned long long v) {
#pragma unroll
  for (int o = 32; o >= 1; o >>= 1) {
    unsigned long long u = __shfl_xor(v, o, 64);
    v = (u < v) ? u : v;
  }
  return v;
}

__device__ inline unsigned f32_orderable(float f) {
  unsigned fb = __float_as_uint(f);
  return (fb & 0x80000000u) ? ~fb : (fb | 0x80000000u);
}
__device__ inline float f32_unorderable(unsigned u) {
  unsigned fb = (u & 0x80000000u) ? (u & 0x7fffffffu) : ~u;
  return __uint_as_float(fb);
}

__device__ inline void edge_basis(const float* __restrict__ pseudo, int e,
                                  float bas[8], int kidx[8]) {
  float v0 = pseudo[e * 3 + 0] * (float)(KS - 1);
  float v1 = pseudo[e * 3 + 1] * (float)(KS - 1);
  float v2 = pseudo[e * 3 + 2] * (float)(KS - 1);
  float l0 = floorf(v0), l1 = floorf(v1), l2 = floorf(v2);
  float f0 = v0 - l0, f1 = v1 - l1, f2 = v2 - l2;
  int i0 = (int)l0, i1 = (int)l1, i2 = (int)l2;
#pragma unroll
  for (int s = 0; s < 8; s++) {
    int b0 = s & 1, b1 = (s >> 1) & 1, b2 = (s >> 2) & 1;
    float bb = (b0 ? f0 : 1.f - f0) * (b1 ? f1 : 1.f - f1) * (b2 ? f2 : 1.f - f2);
    int j0 = i0 + b0; j0 = j0 < 0 ? 0 : (j0 > KS - 1 ? KS - 1 : j0);
    int j1 = i1 + b1; j1 = j1 < 0 ? 0 : (j1 > KS - 1 ? KS - 1 : j1);
    int j2 = i2 + b2; j2 = j2 < 0 ? 0 : (j2 > KS - 1 ? KS - 1 : j2);
    bas[s] = bb;
    kidx[s] = j0 + KS * j1 + KS * KS * j2;
  }
}

// ---------- B1: per-kidx record count (LDS histogram) ----------
__global__ void count_kernel(const float* __restrict__ pseudo,
                             int* __restrict__ hist, int E_) {
  __shared__ int lh[KTOT];
  int tid = threadIdx.x;
  for (int i = tid; i < KTOT; i += 256) lh[i] = 0;
  __syncthreads();
  int e = blockIdx.x * 256 + tid;
  if (e < E_) {
    float bas[8];
    int kidx[8];
    edge_basis(pseudo, e, bas, kidx);
#pragma unroll
    for (int s = 0; s < 8; s++) atomicAdd(&lh[kidx[s]], 1);
  }
  __syncthreads();
  for (int i = tid; i < KTOT; i += 256)
    if (lh[i]) atomicAdd(&hist[i], lh[i]);
}

// ---------- B2: serial scan -> 64-aligned bucket offsets (125 iters only) ----------
__global__ void scan_kernel(const int* __restrict__ hist, int* __restrict__ off,
                            int* __restrict__ cur, int* __restrict__ meta) {
  if (threadIdx.x == 0 && blockIdx.x == 0) {
    int o = 0;
    for (int k = 0; k < KTOT; k++) {
      off[k] = o;
      cur[k] = o;
      o += (hist[k] + 63) & ~63;
    }
    off[KTOT] = o;
    meta[0] = o >> 6;  // number of 64-record blocks
  }
}

// ---------- B3: fill records — hierarchical rank allocation ----------
// LDS-returning atomics give local ranks; ONE global atomic per (block,kidx)
// reserves the chunk (125*nblocks ~ 32K global atomics vs 524K before).
__global__ void fill_kernel(const int* __restrict__ ei,
                            const float* __restrict__ pseudo,
                            int* __restrict__ cur,
                            int* __restrict__ rdst, int* __restrict__ rsrc,
                            float* __restrict__ rbas,
                            float* __restrict__ deg, int E_) {
  __shared__ int lh[KTOT];     // local counts -> per-kidx block totals
  __shared__ int lbase[KTOT];  // global base of this block's chunk
  int tid = threadIdx.x;
  for (int i = tid; i < KTOT; i += 256) lh[i] = 0;
  __syncthreads();

  int e = blockIdx.x * 256 + tid;
  bool valid = e < E_;
  int src = 0, dst = 0;
  float bas[8];
  int kidx[8];
  int lpos[8];
  if (valid) {
    src = ei[e];
    dst = ei[E_ + e];
    edge_basis(pseudo, e, bas, kidx);
#pragma unroll
    for (int s = 0; s < 8; s++) lpos[s] = atomicAdd(&lh[kidx[s]], 1);
  }
  __syncthreads();

  for (int i = tid; i < KTOT; i += 256) {
    int c = lh[i];
    lbase[i] = c ? atomicAdd(&cur[i], c) : 0;
  }
  __syncthreads();

  if (valid) {
#pragma unroll
    for (int s = 0; s < 8; s++) {
      int pos = lbase[kidx[s]] + lpos[s];
      rdst[pos] = dst;
      rsrc[pos] = src;
      rbas[pos] = bas[s];
    }
    atomicAdd(&deg[dst], 1.f);
  }
}

// ---------- B4: grouped GEMM, coalesced-burst atomic epilogue ----------
__global__ __launch_bounds__(256) void grouped_gemm_kernel(
    const float* __restrict__ x, const float* __restrict__ Wf,
    const int* __restrict__ rdst, const int* __restrict__ rsrc,
    const float* __restrict__ rbas, const int* __restrict__ off,
    const int* __restrict__ meta, float* __restrict__ acc) {
  __shared__ float Wt[64][64];   // [i][o]
  __shared__ float Atr[64][64];  // [i][rec], reused as res[rec][o] in epilogue
  __shared__ int kshare;
  int nb = meta[0];
  int bid = blockIdx.x;
  if (bid >= nb) return;
  int tid = threadIdx.x;
  int base = bid << 6;

  if (tid == 0) {
    // largest k with off[k] <= base  (off is 64-aligned, off[KTOT] = total)
    int lo = 0, hi = KTOT;
    while (lo + 1 < hi) {
      int mid = (lo + hi) >> 1;
      if (off[mid] <= base) lo = mid; else hi = mid;
    }
    kshare = lo;
  }

  // stage A^T: Atr[i][rec] = bas * x[src][i]  (pad recs have bas=0)
  {
    int rec = tid >> 2, c16 = (tid & 3) * 16;
    int slot = base + rec;
    float b = rbas[slot];
    int s = rsrc[slot];
    const float* xs = x + (size_t)s * CIN + c16;
    float4 v0 = *(const float4*)xs;
    float4 v1 = *(const float4*)(xs + 4);
    float4 v2 = *(const float4*)(xs + 8);
    float4 v3 = *(const float4*)(xs + 12);
    Atr[c16 + 0][rec] = b * v0.x;  Atr[c16 + 1][rec] = b * v0.y;
    Atr[c16 + 2][rec] = b * v0.z;  Atr[c16 + 3][rec] = b * v0.w;
    Atr[c16 + 4][rec] = b * v1.x;  Atr[c16 + 5][rec] = b * v1.y;
    Atr[c16 + 6][rec] = b * v1.z;  Atr[c16 + 7][rec] = b * v1.w;
    Atr[c16 + 8][rec] = b * v2.x;  Atr[c16 + 9][rec] = b * v2.y;
    Atr[c16 + 10][rec] = b * v2.z; Atr[c16 + 11][rec] = b * v2.w;
    Atr[c16 + 12][rec] = b * v3.x; Atr[c16 + 13][rec] = b * v3.y;
    Atr[c16 + 14][rec] = b * v3.z; Atr[c16 + 15][rec] = b * v3.w;
  }
  __syncthreads();  // kshare visible

  // stage W[k] (row-major [i][o]) — coalesced float4
  {
    int k = kshare;
    int wi = tid >> 2, wo = (tid & 3) * 16;
    const float* wsrc = Wf + (size_t)k * (CIN * COUT) + wi * COUT + wo;
    float4 a = *(const float4*)wsrc;
    float4 b = *(const float4*)(wsrc + 4);
    float4 c = *(const float4*)(wsrc + 8);
    float4 d = *(const float4*)(wsrc + 12);
    *(float4*)&Wt[wi][wo + 0] = a;
    *(float4*)&Wt[wi][wo + 4] = b;
    *(float4*)&Wt[wi][wo + 8] = c;
    *(float4*)&Wt[wi][wo + 12] = d;
  }
  __syncthreads();

  int mg = tid >> 4, og = tid & 15;
  int m = mg * 4, o = og * 4;
  float a_[4][4] = {};
#pragma unroll 16
  for (int kk = 0; kk < 64; kk++) {
    float4 av = *(const float4*)&Atr[kk][m];
    float4 wv = *(const float4*)&Wt[kk][o];
    a_[0][0] = fmaf(av.x, wv.x, a_[0][0]);
    a_[0][1] = fmaf(av.x, wv.y, a_[0][1]);
    a_[0][2] = fmaf(av.x, wv.z, a_[0][2]);
    a_[0][3] = fmaf(av.x, wv.w, a_[0][3]);
    a_[1][0] = fmaf(av.y, wv.x, a_[1][0]);
    a_[1][1] = fmaf(av.y, wv.y, a_[1][1]);
    a_[1][2] = fmaf(av.y, wv.z, a_[1][2]);
    a_[1][3] = fmaf(av.y, wv.w, a_[1][3]);
    a_[2][0] = fmaf(av.z, wv.x, a_[2][0]);
    a_[2][1] = fmaf(av.z, wv.y, a_[2][1]);
    a_[2][2] = fmaf(av.z, wv.z, a_[2][2]);
    a_[2][3] = fmaf(av.z, wv.w, a_[2][3]);
    a_[3][0] = fmaf(av.w, wv.x, a_[3][0]);
    a_[3][1] = fmaf(av.w, wv.y, a_[3][1]);
    a_[3][2] = fmaf(av.w, wv.z, a_[3][2]);
    a_[3][3] = fmaf(av.w, wv.w, a_[3][3]);
  }

  // epilogue: results -> LDS (reuse Atr as res[rec][o]) -> per-row coalesced bursts
  __syncthreads();  // all Atr/Wt reads done
  float* res = &Atr[0][0];
#pragma unroll
  for (int i = 0; i < 4; i++) {
    *(float4*)&res[(m + i) * 64 + o] =
        make_float4(a_[i][0], a_[i][1], a_[i][2], a_[i][3]);
  }
  __syncthreads();

  int wave = tid >> 6, lane = tid & 63;
#pragma unroll 4
  for (int p = 0; p < 16; p++) {
    int r = wave * 16 + p;
    float v = res[r * 64 + lane];
    if (__ballot(v != 0.f) == 0ull) continue;  // skip all-zero pad rows
    int dst = rdst[base + r];
    atomicAdd(&acc[(size_t)dst * COUT + lane], v);  // one 256B burst per row
  }
}

// ---------- node finish: acc/deg + x@root + bias, ELU ----------
__global__ void node_finish_kernel(const float* __restrict__ x,
                                   const float* __restrict__ root,
                                   const float* __restrict__ bias,
                                   const float* __restrict__ acc,
                                   const float* __restrict__ deg,
                                   float* __restrict__ h, int Nx_) {
  int lane = threadIdx.x & 63;
  int n = (int)((blockIdx.x * blockDim.x + threadIdx.x) >> 6);
  if (n >= Nx_) return;
  float xs = x[(size_t)n * CIN + lane];
  float r = 0.f;
#pragma unroll 4
  for (int i = 0; i < CIN; i++) {
    float xv = __shfl(xs, i, 64);
    r = fmaf(xv, root[i * COUT + lane], r);
  }
  float d = deg[n];
  d = d > 1.f ? d : 1.f;
  float o = acc[(size_t)n * COUT + lane] / d + r + bias[lane];
  h[(size_t)n * COUT + lane] = (o > 0.f) ? o : expm1f(o);
}

// ---------- kNN pre-pack: [x0,x1,x2,|x|^2] ----------
__global__ void pack_posx_kernel(const float* __restrict__ pos_x,
                                 float4* __restrict__ pxp, int Nx_) {
  int t = blockIdx.x * blockDim.x + threadIdx.x;
  if (t >= Nx_) return;
  float a0 = pos_x[t * 3 + 0], a1 = pos_x[t * 3 + 1], a2 = pos_x[t * 3 + 2];
  pxp[t] = make_float4(a0, a1, a2, a0 * a0 + a1 * a1 + a2 * a2);
}

// ---------- fused kNN + inverse-distance interp (k-specialized) ----------
__global__ void knn_interp2_kernel(const float* __restrict__ h,
                                   const float4* __restrict__ pxp,
                                   const float* __restrict__ pos_y,
                                   const int* __restrict__ batch_x,
                                   const int* __restrict__ batch_y,
                                   const int* __restrict__ kptr,
                                   float* __restrict__ out,
                                   int Nx_, int Ny_) {
  int lane = threadIdx.x & 63;
  int yy = (int)((blockIdx.x * blockDim.x + threadIdx.x) >> 6);
  if (yy >= Ny_) return;

  float q0 = pos_y[yy * 3 + 0], q1 = pos_y[yy * 3 + 1], q2 = pos_y[yy * 3 + 2];
  float py2 = q0 * q0 + q1 * q1 + q2 * q2;
  int by = batch_y[yy];
  int kk = *kptr;
  kk = kk < 1 ? 1 : (kk > 8 ? 8 : kk);

  float num = 0.f, den = 0.f;

  if (kk <= 3) {
    const float FINF = __uint_as_float(0x7f800000u);
    float bd0 = FINF, bd1 = FINF, bd2 = FINF;
    unsigned bi0 = ~0u, bi1 = ~0u, bi2 = ~0u;

    for (int t0 = 0; t0 < Nx_; t0 += 64) {
      int t = t0 + lane;
      int tc = t < Nx_ ? t : Nx_ - 1;
      float4 p = pxp[tc];
      float dot = fmaf(q0, p.x, fmaf(q1, p.y, q2 * p.z));
      float d2 = fmaf(-2.f, dot, py2 + p.w);
      if (batch_x[tc] != by) d2 = 1e10f;
      if (t >= Nx_) d2 = FINF;

      float kv = d2;
      unsigned ki = (unsigned)t;
      {
        bool lt = kv < bd0;
        float nv = lt ? kv : bd0; float xv = lt ? bd0 : kv;
        unsigned ni = lt ? ki : bi0; unsigned xi = lt ? bi0 : ki;
        bd0 = nv; bi0 = ni; kv = xv; ki = xi;
      }
      {
        bool lt = kv < bd1;
        float nv = lt ? kv : bd1; float xv = lt ? bd1 : kv;
        unsigned ni = lt ? ki : bi1; unsigned xi = lt ? bi1 : ki;
        bd1 = nv; bi1 = ni; kv = xv; ki = xi;
      }
      {
        bool lt = kv < bd2;
        float nv = lt ? kv : bd2;
        unsigned ni = lt ? ki : bi2;
        bd2 = nv; bi2 = ni;
      }
    }

    unsigned long long c0 = (((unsigned long long)f32_orderable(bd0)) << 32) | bi0;
    unsigned long long c1 = (((unsigned long long)f32_orderable(bd1)) << 32) | bi1;
    unsigned long long c2 = (((unsigned long long)f32_orderable(bd2)) << 32) | bi2;

    for (int j = 0; j < kk; j++) {
      unsigned long long m = wmin64(c0);
      if (c0 == m) { c0 = c1; c1 = c2; c2 = ~0ull; }
      unsigned u = (unsigned)(m >> 32);
      int idx = (int)(m & 0xffffffffu);
      idx = (idx < 0 || idx >= Nx_) ? 0 : idx;
      float d2 = f32_unorderable(u);
      float w = 1.f / fmaxf(d2, 1e-16f);
      num = fmaf(w, h[(size_t)idx * COUT + lane], num);
      den += w;
    }
  } else {
    unsigned long long best[8];
#pragma unroll
    for (int j = 0; j < 8; j++) best[j] = ~0ull;

    for (int t0 = 0; t0 < Nx_; t0 += 64) {
      int t = t0 + lane;
      unsigned long long key = ~0ull;
      if (t < Nx_) {
        float4 p = pxp[t];
        float dot = fmaf(q0, p.x, fmaf(q1, p.y, q2 * p.z));
        float d2 = fmaf(-2.f, dot, py2 + p.w);
        if (batch_x[t] != by) d2 = 1e10f;
        key = (((unsigned long long)f32_orderable(d2)) << 32) | (unsigned)t;
      }
      if (key < best[7]) {
#pragma unroll
        for (int j = 0; j < 8; j++) {
          unsigned long long mn = key < best[j] ? key : best[j];
          unsigned long long mx = key < best[j] ? best[j] : key;
          best[j] = mn;
          key = mx;
        }
      }
    }

    for (int j = 0; j < kk; j++) {
      unsigned long long m = wmin64(best[0]);
      if (best[0] == m) {
#pragma unroll
        for (int t = 0; t < 7; t++) best[t] = best[t + 1];
        best[7] = ~0ull;
      }
      unsigned u = (unsigned)(m >> 32);
      int idx = (int)(m & 0xffffffffu);
      idx = (idx < 0 || idx >= Nx_) ? 0 : idx;
      float d2 = f32_unorderable(u);
      float w = 1.f / fmaxf(d2, 1e-16f);
      num = fmaf(w, h[(size_t)idx * COUT + lane], num);
      den += w;
    }
  }

  out[(size_t)yy * COUT + lane] = num / den;
}

extern "C" void kernel_launch(void* const* d_in, const int* in_sizes, int n_in,
                              void* d_out, int out_size, void* d_ws, size_t ws_size,
                              hipStream_t stream) {
  const float* x = (const float*)d_in[0];
  const float* pos_x = (const float*)d_in[1];
  const float* pos_y = (const float*)d_in[2];
  const int* eidx = (const int*)d_in[3];
  const float* pseudo = (const float*)d_in[4];
  const int* batch_x = (const int*)d_in[5];
  const int* batch_y = (const int*)d_in[6];
  const float* W = (const float*)d_in[7];   // [125,64,64]
  const float* root = (const float*)d_in[8];
  const float* bias = (const float*)d_in[9];
  const int* kptr = (const int*)d_in[10];

  int Nx = in_sizes[0] / CIN;
  int Ny = in_sizes[2] / 3;
  int E = in_sizes[3] / 2;

  int maxslots = E * 8 + KTOT * 64;  // padded record capacity
  int maxblocks = maxslots / 64;

  // ws layout (4B units):
  // acc[Nx*64] | deg[Nx] | h[Nx*64] | pxp[Nx*4] | hist[128] | off[128] |
  // cur[128] | meta[16] | rdst[ms] | rsrc[ms] | rbas[ms]
  float* acc = (float*)d_ws;
  float* deg = acc + (size_t)Nx * COUT;
  float* h = deg + Nx;
  float4* pxp = (float4*)(h + (size_t)Nx * COUT);
  int* hist = (int*)(pxp + Nx);
  int* off = hist + 128;
  int* cur = off + 128;
  int* meta = cur + 128;
  int* rdst = meta + 16;
  int* rsrc = rdst + maxslots;
  float* rbas = (float*)(rsrc + maxslots);

  float* out = (float*)d_out;

  // zero: acc+deg, hist, rec arrays (rdst|rsrc|rbas contiguous)
  hipMemsetAsync(acc, 0, ((size_t)Nx * COUT + Nx) * sizeof(float), stream);
  hipMemsetAsync(hist, 0, 128 * sizeof(int), stream);
  hipMemsetAsync(rdst, 0, (size_t)3 * maxslots * sizeof(int), stream);

  int eblocks = (E + 255) / 256;
  count_kernel<<<eblocks, 256, 0, stream>>>(pseudo, hist, E);
  scan_kernel<<<1, 64, 0, stream>>>(hist, off, cur, meta);
  fill_kernel<<<eblocks, 256, 0, stream>>>(eidx, pseudo, cur, rdst, rsrc, rbas, deg, E);
  grouped_gemm_kernel<<<maxblocks, 256, 0, stream>>>(x, W, rdst, rsrc, rbas,
                                                     off, meta, acc);
  {
    int blocks = (Nx * WAVE + 255) / 256;
    node_finish_kernel<<<blocks, 256, 0, stream>>>(x, root, bias, acc, deg, h, Nx);
  }
  pack_posx_kernel<<<(Nx + 255) / 256, 256, 0, stream>>>(pos_x, pxp, Nx);
  {
    int blocks = (Ny * WAVE + 255) / 256;
    knn_interp2_kernel<<<blocks, 256, 0, stream>>>(h, pxp, pos_y, batch_x, batch_y,
                                                   kptr, out, Nx, Ny);
  }
}

// Round 7
// 160.030 us; speedup vs baseline: 9.7863x; 1.5741x over previous
//
#include <hip/hip_runtime.h>
#include <stdint.h>

#define WAVE 64
#define CIN 64
#define COUT 64
#define KS 5
#define KTOT 125  // 5^3

__device__ inline unsigned long long wmin64(unsigned long long v) {
#pragma unroll
  for (int o = 32; o >= 1; o >>= 1) {
    unsigned long long u = __shfl_xor(v, o, 64);
    v = (u < v) ? u : v;
  }
  return v;
}

__device__ inline unsigned f32_orderable(float f) {
  unsigned fb = __float_as_uint(f);
  return (fb & 0x80000000u) ? ~fb : (fb | 0x80000000u);
}
__device__ inline float f32_unorderable(unsigned u) {
  unsigned fb = (u & 0x80000000u) ? (u & 0x7fffffffu) : ~u;
  return __uint_as_float(fb);
}

__device__ inline void edge_basis(const float* __restrict__ pseudo, int e,
                                  float bas[8], int kidx[8]) {
  float v0 = pseudo[e * 3 + 0] * (float)(KS - 1);
  float v1 = pseudo[e * 3 + 1] * (float)(KS - 1);
  float v2 = pseudo[e * 3 + 2] * (float)(KS - 1);
  float l0 = floorf(v0), l1 = floorf(v1), l2 = floorf(v2);
  float f0 = v0 - l0, f1 = v1 - l1, f2 = v2 - l2;
  int i0 = (int)l0, i1 = (int)l1, i2 = (int)l2;
#pragma unroll
  for (int s = 0; s < 8; s++) {
    int b0 = s & 1, b1 = (s >> 1) & 1, b2 = (s >> 2) & 1;
    float bb = (b0 ? f0 : 1.f - f0) * (b1 ? f1 : 1.f - f1) * (b2 ? f2 : 1.f - f2);
    int j0 = i0 + b0; j0 = j0 < 0 ? 0 : (j0 > KS - 1 ? KS - 1 : j0);
    int j1 = i1 + b1; j1 = j1 < 0 ? 0 : (j1 > KS - 1 ? KS - 1 : j1);
    int j2 = i2 + b2; j2 = j2 < 0 ? 0 : (j2 > KS - 1 ? KS - 1 : j2);
    bas[s] = bb;
    kidx[s] = j0 + KS * j1 + KS * KS * j2;
  }
}

// ---------- S1: xW[n,k,:] = x[n] @ W[k]  — batched dense GEMM, plain stores ----------
__global__ __launch_bounds__(256) void xw_gemm_kernel(const float* __restrict__ x,
                                                      const float* __restrict__ Wf,
                                                      float* __restrict__ xw,
                                                      int Nx_) {
  __shared__ float Xtr[64][64];  // [i][row]
  __shared__ float Wt[64][64];   // [i][o]
  int tid = threadIdx.x;
  int n0 = blockIdx.x * 64;
  int k = blockIdx.y;

  // stage W[k] (row-major [i][o]) — coalesced float4
  {
    int wi = tid >> 2, wo = (tid & 3) * 16;
    const float* wsrc = Wf + (size_t)k * (CIN * COUT) + wi * COUT + wo;
    float4 a = *(const float4*)wsrc;
    float4 b = *(const float4*)(wsrc + 4);
    float4 c = *(const float4*)(wsrc + 8);
    float4 d = *(const float4*)(wsrc + 12);
    *(float4*)&Wt[wi][wo + 0] = a;
    *(float4*)&Wt[wi][wo + 4] = b;
    *(float4*)&Wt[wi][wo + 8] = c;
    *(float4*)&Wt[wi][wo + 12] = d;
  }
  // stage X^T: Xtr[i][row]
  {
    int rec = tid >> 2, c16 = (tid & 3) * 16;
    int row = n0 + rec;
    if (row >= Nx_) row = Nx_ - 1;
    const float* xs = x + (size_t)row * CIN + c16;
    float4 v0 = *(const float4*)xs;
    float4 v1 = *(const float4*)(xs + 4);
    float4 v2 = *(const float4*)(xs + 8);
    float4 v3 = *(const float4*)(xs + 12);
    Xtr[c16 + 0][rec] = v0.x;  Xtr[c16 + 1][rec] = v0.y;
    Xtr[c16 + 2][rec] = v0.z;  Xtr[c16 + 3][rec] = v0.w;
    Xtr[c16 + 4][rec] = v1.x;  Xtr[c16 + 5][rec] = v1.y;
    Xtr[c16 + 6][rec] = v1.z;  Xtr[c16 + 7][rec] = v1.w;
    Xtr[c16 + 8][rec] = v2.x;  Xtr[c16 + 9][rec] = v2.y;
    Xtr[c16 + 10][rec] = v2.z; Xtr[c16 + 11][rec] = v2.w;
    Xtr[c16 + 12][rec] = v3.x; Xtr[c16 + 13][rec] = v3.y;
    Xtr[c16 + 14][rec] = v3.z; Xtr[c16 + 15][rec] = v3.w;
  }
  __syncthreads();

  int mg = tid >> 4, og = tid & 15;
  int m = mg * 4, o = og * 4;
  float a_[4][4] = {};
#pragma unroll 16
  for (int kk = 0; kk < 64; kk++) {
    float4 av = *(const float4*)&Xtr[kk][m];
    float4 wv = *(const float4*)&Wt[kk][o];
    a_[0][0] = fmaf(av.x, wv.x, a_[0][0]);
    a_[0][1] = fmaf(av.x, wv.y, a_[0][1]);
    a_[0][2] = fmaf(av.x, wv.z, a_[0][2]);
    a_[0][3] = fmaf(av.x, wv.w, a_[0][3]);
    a_[1][0] = fmaf(av.y, wv.x, a_[1][0]);
    a_[1][1] = fmaf(av.y, wv.y, a_[1][1]);
    a_[1][2] = fmaf(av.y, wv.z, a_[1][2]);
    a_[1][3] = fmaf(av.y, wv.w, a_[1][3]);
    a_[2][0] = fmaf(av.z, wv.x, a_[2][0]);
    a_[2][1] = fmaf(av.z, wv.y, a_[2][1]);
    a_[2][2] = fmaf(av.z, wv.z, a_[2][2]);
    a_[2][3] = fmaf(av.z, wv.w, a_[2][3]);
    a_[3][0] = fmaf(av.w, wv.x, a_[3][0]);
    a_[3][1] = fmaf(av.w, wv.y, a_[3][1]);
    a_[3][2] = fmaf(av.w, wv.z, a_[3][2]);
    a_[3][3] = fmaf(av.w, wv.w, a_[3][3]);
  }

  // direct store: xw[(row*125 + k)*64 + o..o+3]
#pragma unroll
  for (int i = 0; i < 4; i++) {
    int row = n0 + m + i;
    if (row < Nx_) {
      *(float4*)&xw[((size_t)row * KTOT + k) * COUT + o] =
          make_float4(a_[i][0], a_[i][1], a_[i][2], a_[i][3]);
    }
  }
}

// ---------- S2: per-edge gather-sum + single atomic burst ----------
__global__ void edge_sum_kernel(const int* __restrict__ ei,
                                const float* __restrict__ pseudo,
                                const float* __restrict__ xw,
                                float* __restrict__ acc,
                                float* __restrict__ deg, int E_) {
  int lane = threadIdx.x & 63;
  int e = (int)((blockIdx.x * blockDim.x + threadIdx.x) >> 6);
  if (e >= E_) return;
  int src = ei[e];
  int dst = ei[E_ + e];
  float bas[8];
  int kidx[8];
  edge_basis(pseudo, e, bas, kidx);

  const float* bx = xw + (size_t)src * (KTOT * COUT) + lane;
  float y = 0.f;
#pragma unroll
  for (int s = 0; s < 8; s++) {
    y = fmaf(bas[s], bx[kidx[s] * COUT], y);
  }
  atomicAdd(&acc[(size_t)dst * COUT + lane], y);
  if (lane == 0) atomicAdd(&deg[dst], 1.f);
}

// ---------- node finish: acc/deg + x@root + bias, ELU ----------
__global__ void node_finish_kernel(const float* __restrict__ x,
                                   const float* __restrict__ root,
                                   const float* __restrict__ bias,
                                   const float* __restrict__ acc,
                                   const float* __restrict__ deg,
                                   float* __restrict__ h, int Nx_) {
  int lane = threadIdx.x & 63;
  int n = (int)((blockIdx.x * blockDim.x + threadIdx.x) >> 6);
  if (n >= Nx_) return;
  float xs = x[(size_t)n * CIN + lane];
  float r = 0.f;
#pragma unroll 4
  for (int i = 0; i < CIN; i++) {
    float xv = __shfl(xs, i, 64);
    r = fmaf(xv, root[i * COUT + lane], r);
  }
  float d = deg[n];
  d = d > 1.f ? d : 1.f;
  float o = acc[(size_t)n * COUT + lane] / d + r + bias[lane];
  h[(size_t)n * COUT + lane] = (o > 0.f) ? o : expm1f(o);
}

// ---------- kNN pre-pack: [x0,x1,x2,|x|^2] ----------
__global__ void pack_posx_kernel(const float* __restrict__ pos_x,
                                 float4* __restrict__ pxp, int Nx_) {
  int t = blockIdx.x * blockDim.x + threadIdx.x;
  if (t >= Nx_) return;
  float a0 = pos_x[t * 3 + 0], a1 = pos_x[t * 3 + 1], a2 = pos_x[t * 3 + 2];
  pxp[t] = make_float4(a0, a1, a2, a0 * a0 + a1 * a1 + a2 * a2);
}

// ---------- fused kNN + inverse-distance interp (k-specialized) ----------
__global__ void knn_interp2_kernel(const float* __restrict__ h,
                                   const float4* __restrict__ pxp,
                                   const float* __restrict__ pos_y,
                                   const int* __restrict__ batch_x,
                                   const int* __restrict__ batch_y,
                                   const int* __restrict__ kptr,
                                   float* __restrict__ out,
                                   int Nx_, int Ny_) {
  int lane = threadIdx.x & 63;
  int yy = (int)((blockIdx.x * blockDim.x + threadIdx.x) >> 6);
  if (yy >= Ny_) return;

  float q0 = pos_y[yy * 3 + 0], q1 = pos_y[yy * 3 + 1], q2 = pos_y[yy * 3 + 2];
  float py2 = q0 * q0 + q1 * q1 + q2 * q2;
  int by = batch_y[yy];
  int kk = *kptr;
  kk = kk < 1 ? 1 : (kk > 8 ? 8 : kk);

  float num = 0.f, den = 0.f;

  if (kk <= 3) {
    const float FINF = __uint_as_float(0x7f800000u);
    float bd0 = FINF, bd1 = FINF, bd2 = FINF;
    unsigned bi0 = ~0u, bi1 = ~0u, bi2 = ~0u;

    for (int t0 = 0; t0 < Nx_; t0 += 64) {
      int t = t0 + lane;
      int tc = t < Nx_ ? t : Nx_ - 1;
      float4 p = pxp[tc];
      float dot = fmaf(q0, p.x, fmaf(q1, p.y, q2 * p.z));
      float d2 = fmaf(-2.f, dot, py2 + p.w);
      if (batch_x[tc] != by) d2 = 1e10f;
      if (t >= Nx_) d2 = FINF;

      float kv = d2;
      unsigned ki = (unsigned)t;
      {
        bool lt = kv < bd0;
        float nv = lt ? kv : bd0; float xv = lt ? bd0 : kv;
        unsigned ni = lt ? ki : bi0; unsigned xi = lt ? bi0 : ki;
        bd0 = nv; bi0 = ni; kv = xv; ki = xi;
      }
      {
        bool lt = kv < bd1;
        float nv = lt ? kv : bd1; float xv = lt ? bd1 : kv;
        unsigned ni = lt ? ki : bi1; unsigned xi = lt ? bi1 : ki;
        bd1 = nv; bi1 = ni; kv = xv; ki = xi;
      }
      {
        bool lt = kv < bd2;
        float nv = lt ? kv : bd2;
        unsigned ni = lt ? ki : bi2;
        bd2 = nv; bi2 = ni;
      }
    }

    unsigned long long c0 = (((unsigned long long)f32_orderable(bd0)) << 32) | bi0;
    unsigned long long c1 = (((unsigned long long)f32_orderable(bd1)) << 32) | bi1;
    unsigned long long c2 = (((unsigned long long)f32_orderable(bd2)) << 32) | bi2;

    for (int j = 0; j < kk; j++) {
      unsigned long long m = wmin64(c0);
      if (c0 == m) { c0 = c1; c1 = c2; c2 = ~0ull; }
      unsigned u = (unsigned)(m >> 32);
      int idx = (int)(m & 0xffffffffu);
      idx = (idx < 0 || idx >= Nx_) ? 0 : idx;
      float d2 = f32_unorderable(u);
      float w = 1.f / fmaxf(d2, 1e-16f);
      num = fmaf(w, h[(size_t)idx * COUT + lane], num);
      den += w;
    }
  } else {
    unsigned long long best[8];
#pragma unroll
    for (int j = 0; j < 8; j++) best[j] = ~0ull;

    for (int t0 = 0; t0 < Nx_; t0 += 64) {
      int t = t0 + lane;
      unsigned long long key = ~0ull;
      if (t < Nx_) {
        float4 p = pxp[t];
        float dot = fmaf(q0, p.x, fmaf(q1, p.y, q2 * p.z));
        float d2 = fmaf(-2.f, dot, py2 + p.w);
        if (batch_x[t] != by) d2 = 1e10f;
        key = (((unsigned long long)f32_orderable(d2)) << 32) | (unsigned)t;
      }
      if (key < best[7]) {
#pragma unroll
        for (int j = 0; j < 8; j++) {
          unsigned long long mn = key < best[j] ? key : best[j];
          unsigned long long mx = key < best[j] ? best[j] : key;
          best[j] = mn;
          key = mx;
        }
      }
    }

    for (int j = 0; j < kk; j++) {
      unsigned long long m = wmin64(best[0]);
      if (best[0] == m) {
#pragma unroll
        for (int t = 0; t < 7; t++) best[t] = best[t + 1];
        best[7] = ~0ull;
      }
      unsigned u = (unsigned)(m >> 32);
      int idx = (int)(m & 0xffffffffu);
      idx = (idx < 0 || idx >= Nx_) ? 0 : idx;
      float d2 = f32_unorderable(u);
      float w = 1.f / fmaxf(d2, 1e-16f);
      num = fmaf(w, h[(size_t)idx * COUT + lane], num);
      den += w;
    }
  }

  out[(size_t)yy * COUT + lane] = num / den;
}

extern "C" void kernel_launch(void* const* d_in, const int* in_sizes, int n_in,
                              void* d_out, int out_size, void* d_ws, size_t ws_size,
                              hipStream_t stream) {
  const float* x = (const float*)d_in[0];
  const float* pos_x = (const float*)d_in[1];
  const float* pos_y = (const float*)d_in[2];
  const int* eidx = (const int*)d_in[3];
  const float* pseudo = (const float*)d_in[4];
  const int* batch_x = (const int*)d_in[5];
  const int* batch_y = (const int*)d_in[6];
  const float* W = (const float*)d_in[7];   // [125,64,64]
  const float* root = (const float*)d_in[8];
  const float* bias = (const float*)d_in[9];
  const int* kptr = (const int*)d_in[10];

  int Nx = in_sizes[0] / CIN;
  int Ny = in_sizes[2] / 3;
  int E = in_sizes[3] / 2;

  // ws layout (4B units): acc[Nx*64] | deg[Nx] | h[Nx*64] | pxp[Nx*4] | xw[Nx*125*64]
  float* acc = (float*)d_ws;
  float* deg = acc + (size_t)Nx * COUT;
  float* h = deg + Nx;
  float4* pxp = (float4*)(h + (size_t)Nx * COUT);
  float* xw = (float*)(pxp + Nx);

  float* out = (float*)d_out;

  // zero acc + deg (contiguous); xw is fully written by xw_gemm
  hipMemsetAsync(acc, 0, ((size_t)Nx * COUT + Nx) * sizeof(float), stream);

  {
    dim3 grid((Nx + 63) / 64, KTOT);
    xw_gemm_kernel<<<grid, 256, 0, stream>>>(x, W, xw, Nx);
  }
  {
    int blocks = (E * WAVE + 255) / 256;
    edge_sum_kernel<<<blocks, 256, 0, stream>>>(eidx, pseudo, xw, acc, deg, E);
  }
  {
    int blocks = (Nx * WAVE + 255) / 256;
    node_finish_kernel<<<blocks, 256, 0, stream>>>(x, root, bias, acc, deg, h, Nx);
  }
  pack_posx_kernel<<<(Nx + 255) / 256, 256, 0, stream>>>(pos_x, pxp, Nx);
  {
    int blocks = (Ny * WAVE + 255) / 256;
    knn_interp2_kernel<<<blocks, 256, 0, stream>>>(h, pxp, pos_y, batch_x, batch_y,
                                                   kptr, out, Nx, Ny);
  }
}